// Round 1
// baseline (416.774 us; speedup 1.0000x reference)
//
#include <hip/hip_runtime.h>

#define N_NODES   100000
#define N_EDGES   800000
#define NODE_DIM  64
#define EDGE_DIM  64
#define GEO_DIM   8
#define GEO_OUT   32
#define COND_DIM  512
#define N_GRAPHS  64

typedef short  bf8   __attribute__((ext_vector_type(8)));   // 8 bf16 in 4 VGPRs
typedef float  f32x4 __attribute__((ext_vector_type(4)));
typedef unsigned short u16x8 __attribute__((ext_vector_type(8)));

__device__ __forceinline__ float b2f(unsigned short u) {
    return __uint_as_float(((unsigned)u) << 16);
}
__device__ __forceinline__ short f2b(float f) {   // round-to-nearest-even f32->bf16
    unsigned u = __float_as_uint(f);
    u = (u + 0x7FFFu + ((u >> 16) & 1u)) >> 16;
    return (short)u;
}
__device__ __forceinline__ float rdlane(float v, int l) {
    return __int_as_float(__builtin_amdgcn_readlane(__float_as_int(v), l));
}

// ---------------------------------------------------------------------------
// prep: blocks 0..63 -> gamma/beta2 per graph; block 64 -> Bmat (bf16 96x64)
//   gamma[g][j] = (cond[g]@Wc)[j] + 1
//   beta2[g][j] = (cond[g]@Wc)[64+j] + cvec[j]*gamma[g][j],  cvec = bg @ Wx[64:96]
//   Bmat rows 0..63  = bf16(Wx[0:64])
//   Bmat rows 64..71 = bf16(Wg @ Wx[64:96])      (geo fold)
//   Bmat rows 72..95 = 0                          (K padding for 3rd MFMA chunk)
// ---------------------------------------------------------------------------
__global__ __launch_bounds__(128) void prep_kernel(
        const float* __restrict__ cond, const float* __restrict__ Wc,
        const float* __restrict__ bc,   const float* __restrict__ Wg,
        const float* __restrict__ bg,   const float* __restrict__ Wx,
        float* __restrict__ gamma, float* __restrict__ beta2,
        unsigned short* __restrict__ Bmat) {
    int t = threadIdx.x;
    int g = blockIdx.x;
    if (g < N_GRAPHS) {
        __shared__ float condl[COND_DIM];
        __shared__ float gbl[128];
        for (int i = t; i < COND_DIM; i += 128) condl[i] = cond[g * COND_DIM + i];
        __syncthreads();
        float acc = bc[t];
        #pragma unroll 8
        for (int k = 0; k < COND_DIM; ++k) acc += condl[k] * Wc[k * 128 + t];
        gbl[t] = acc;
        __syncthreads();
        if (t < 64) {
            float gam = gbl[t] + 1.0f;
            float bet = gbl[64 + t];
            float cv = 0.0f;
            #pragma unroll
            for (int i = 0; i < GEO_OUT; ++i) cv += bg[i] * Wx[(64 + i) * 64 + t];
            gamma[g * 64 + t] = gam;
            beta2[g * 64 + t] = bet + cv * gam;
        }
    } else {
        for (int idx = t; idx < 64 * 64; idx += 128)
            Bmat[idx] = (unsigned short)f2b(Wx[idx]);
        for (int idx = t; idx < 8 * 64; idx += 128) {
            int r = idx >> 6, n = idx & 63;
            float s = 0.f;
            #pragma unroll
            for (int i = 0; i < GEO_OUT; ++i) s += Wg[r * GEO_OUT + i] * Wx[(64 + i) * 64 + n];
            Bmat[(64 + r) * 64 + n] = (unsigned short)f2b(s);
        }
        for (int idx = t; idx < 24 * 64; idx += 128)
            Bmat[72 * 64 + idx] = 0;
    }
}

// ---------------------------------------------------------------------------
// nproj: n_projb[n][j] = bf16( node_feats[n] @ Wn[:,j] + bn[j] )
// one wave per node (grid-stride); Wn column held in 64 VGPRs per lane,
// node row broadcast via readlane; 4-way accumulator ILP.
// ---------------------------------------------------------------------------
__global__ __launch_bounds__(256) void nproj_kernel(
        const float* __restrict__ nf, const float* __restrict__ Wn,
        const float* __restrict__ bn, unsigned short* __restrict__ nprojb) {
    int lane = threadIdx.x & 63;
    int wid    = (blockIdx.x * blockDim.x + threadIdx.x) >> 6;
    int nwaves = (gridDim.x * blockDim.x) >> 6;
    float wcol[64];
    #pragma unroll
    for (int k = 0; k < 64; ++k) wcol[k] = Wn[k * 64 + lane];
    float bnl = bn[lane];
    for (int node = wid; node < N_NODES; node += nwaves) {
        float v = nf[(size_t)node * 64 + lane];
        float a0 = 0.f, a1 = 0.f, a2 = 0.f, a3 = bnl;
        #pragma unroll
        for (int k = 0; k < 64; k += 4) {
            a0 = fmaf(rdlane(v, k    ), wcol[k    ], a0);
            a1 = fmaf(rdlane(v, k + 1), wcol[k + 1], a1);
            a2 = fmaf(rdlane(v, k + 2), wcol[k + 2], a2);
            a3 = fmaf(rdlane(v, k + 3), wcol[k + 3], a3);
        }
        nprojb[(size_t)node * 64 + lane] = (unsigned short)f2b((a0 + a1) + (a2 + a3));
    }
}

// ---------------------------------------------------------------------------
// edge_main: per wave, tile of 16 edges.
//   A (16 x 96): rows = edges; k 0..63 = nproj[src]*nproj[dst] (bf16 gather),
//                k 64..71 = e_geo, k 72..95 = 0
//   B = Bmat (96 x 64 bf16).  12 x mfma_f32_16x16x32_bf16 (3 K-chunks x 4 N-tiles)
//   epilogue: relu(x*gamma[b] + beta2[b]) in C-layout (col=lane&15, row=q*4+reg)
// ---------------------------------------------------------------------------
__global__ __launch_bounds__(256) void edge_kernel(
        const unsigned short* __restrict__ nprojb,
        const int*   __restrict__ eidx,
        const float* __restrict__ egeo,
        const int*   __restrict__ ebatch,
        const unsigned short* __restrict__ Bmat,
        const float* __restrict__ gamma,
        const float* __restrict__ beta2,
        float* __restrict__ out) {
    int lane = threadIdx.x & 63;
    int q  = lane >> 4;
    int mm = lane & 15;
    int wid    = (blockIdx.x * blockDim.x + threadIdx.x) >> 6;
    int nwaves = (gridDim.x * blockDim.x) >> 6;

    // B fragments: B[k = c*32 + q*8 + j][n = t*16 + mm]
    bf8 bfrag[3][4];
    #pragma unroll
    for (int c = 0; c < 3; ++c)
        #pragma unroll
        for (int t = 0; t < 4; ++t)
            #pragma unroll
            for (int j = 0; j < 8; ++j)
                bfrag[c][t][j] = (short)Bmat[(c * 32 + q * 8 + j) * 64 + t * 16 + mm];

    const int NTILES = N_EDGES / 16;
    for (int tile = wid; tile < NTILES; tile += nwaves) {
        int e0 = tile * 16;
        int e  = e0 + mm;                    // this lane's A-row edge
        int s = eidx[e];
        int d = eidx[N_EDGES + e];
        const u16x8* ps = (const u16x8*)(nprojb + (size_t)s * 64 + q * 8);
        const u16x8* pd = (const u16x8*)(nprojb + (size_t)d * 64 + q * 8);
        u16x8 s0 = ps[0], s1 = ps[4];        // k-chunk 0 (q*8..) and 1 (+32)
        u16x8 d0 = pd[0], d1 = pd[4];
        bf8 a0, a1, a2;
        #pragma unroll
        for (int j = 0; j < 8; ++j) {
            a0[j] = f2b(b2f(s0[j]) * b2f(d0[j]));
            a1[j] = f2b(b2f(s1[j]) * b2f(d1[j]));
            a2[j] = 0;
        }
        if (q == 0) {                        // k = 64..71 -> e_geo[e][0..7]
            f32x4 g0 = *(const f32x4*)(egeo + (size_t)e * 8);
            f32x4 g1 = *(const f32x4*)(egeo + (size_t)e * 8 + 4);
            #pragma unroll
            for (int j = 0; j < 4; ++j) { a2[j] = f2b(g0[j]); a2[4 + j] = f2b(g1[j]); }
        }

        f32x4 acc[4];
        #pragma unroll
        for (int t = 0; t < 4; ++t) {
            f32x4 c = {0.f, 0.f, 0.f, 0.f};
            c = __builtin_amdgcn_mfma_f32_16x16x32_bf16(a0, bfrag[0][t], c, 0, 0, 0);
            c = __builtin_amdgcn_mfma_f32_16x16x32_bf16(a1, bfrag[1][t], c, 0, 0, 0);
            c = __builtin_amdgcn_mfma_f32_16x16x32_bf16(a2, bfrag[2][t], c, 0, 0, 0);
            acc[t] = c;
        }

        #pragma unroll
        for (int i = 0; i < 4; ++i) {
            int row = q * 4 + i;             // C/D row = (lane>>4)*4 + reg
            int er  = e0 + row;
            int b   = ebatch[er];
            const float* gp = gamma + b * 64;
            const float* bp = beta2 + b * 64;
            size_t ob = (size_t)er * 64;
            #pragma unroll
            for (int t = 0; t < 4; ++t) {
                int col = t * 16 + mm;
                float v = fmaf(acc[t][i], gp[col], bp[col]);
                out[ob + col] = v > 0.f ? v : 0.f;
            }
        }
    }
}

extern "C" void kernel_launch(void* const* d_in, const int* in_sizes, int n_in,
                              void* d_out, int out_size, void* d_ws, size_t ws_size,
                              hipStream_t stream) {
    const float* node_feats = (const float*)d_in[0];
    const int*   edge_index = (const int*)  d_in[1];
    const float* e_geo      = (const float*)d_in[2];
    const float* cond       = (const float*)d_in[3];
    const int*   ebatch     = (const int*)  d_in[4];
    const float* Wn         = (const float*)d_in[5];
    const float* bn         = (const float*)d_in[6];
    const float* Wg         = (const float*)d_in[7];
    const float* bg         = (const float*)d_in[8];
    const float* Wc         = (const float*)d_in[9];
    const float* bc         = (const float*)d_in[10];
    const float* Wx         = (const float*)d_in[11];
    float* out = (float*)d_out;

    char* ws = (char*)d_ws;
    float*          gamma  = (float*)(ws);                    // 16384 B
    float*          beta2  = (float*)(ws + 16384);            // 16384 B
    unsigned short* Bmat   = (unsigned short*)(ws + 32768);   // 12288 B
    unsigned short* nprojb = (unsigned short*)(ws + 49152);   // 12.8 MB

    hipLaunchKernelGGL(prep_kernel, dim3(65), dim3(128), 0, stream,
                       cond, Wc, bc, Wg, bg, Wx, gamma, beta2, Bmat);
    hipLaunchKernelGGL(nproj_kernel, dim3(512), dim3(256), 0, stream,
                       node_feats, Wn, bn, nprojb);
    hipLaunchKernelGGL(edge_kernel, dim3(1024), dim3(256), 0, stream,
                       nprojb, edge_index, e_geo, ebatch, Bmat, gamma, beta2, out);
}

// Round 2
// 387.186 us; speedup vs baseline: 1.0764x; 1.0764x over previous
//
#include <hip/hip_runtime.h>

#define N_NODES   100000
#define N_EDGES   800000
#define NODE_DIM  64
#define EDGE_DIM  64
#define GEO_DIM   8
#define GEO_OUT   32
#define COND_DIM  512
#define N_GRAPHS  64

typedef short  bf8   __attribute__((ext_vector_type(8)));   // 8 bf16 in 4 VGPRs
typedef float  f32x4 __attribute__((ext_vector_type(4)));
typedef unsigned short u16x8 __attribute__((ext_vector_type(8)));

__device__ __forceinline__ float b2f(unsigned short u) {
    return __uint_as_float(((unsigned)u) << 16);
}
__device__ __forceinline__ short f2b(float f) {   // round-to-nearest-even f32->bf16
    unsigned u = __float_as_uint(f);
    u = (u + 0x7FFFu + ((u >> 16) & 1u)) >> 16;
    return (short)u;
}
__device__ __forceinline__ float rdlane(float v, int l) {
    return __int_as_float(__builtin_amdgcn_readlane(__float_as_int(v), l));
}

// ---------------------------------------------------------------------------
// prep: blocks 0..63 -> gamma/beta2 per graph; block 64 -> Bmat (bf16 96x64)
// ---------------------------------------------------------------------------
__global__ __launch_bounds__(128) void prep_kernel(
        const float* __restrict__ cond, const float* __restrict__ Wc,
        const float* __restrict__ bc,   const float* __restrict__ Wg,
        const float* __restrict__ bg,   const float* __restrict__ Wx,
        float* __restrict__ gamma, float* __restrict__ beta2,
        unsigned short* __restrict__ Bmat) {
    int t = threadIdx.x;
    int g = blockIdx.x;
    if (g < N_GRAPHS) {
        __shared__ float condl[COND_DIM];
        __shared__ float gbl[128];
        for (int i = t; i < COND_DIM; i += 128) condl[i] = cond[g * COND_DIM + i];
        __syncthreads();
        float acc = bc[t];
        #pragma unroll 8
        for (int k = 0; k < COND_DIM; ++k) acc += condl[k] * Wc[k * 128 + t];
        gbl[t] = acc;
        __syncthreads();
        if (t < 64) {
            float gam = gbl[t] + 1.0f;
            float bet = gbl[64 + t];
            float cv = 0.0f;
            #pragma unroll
            for (int i = 0; i < GEO_OUT; ++i) cv += bg[i] * Wx[(64 + i) * 64 + t];
            gamma[g * 64 + t] = gam;
            beta2[g * 64 + t] = bet + cv * gam;
        }
    } else {
        for (int idx = t; idx < 64 * 64; idx += 128)
            Bmat[idx] = (unsigned short)f2b(Wx[idx]);
        for (int idx = t; idx < 8 * 64; idx += 128) {
            int r = idx >> 6, n = idx & 63;
            float s = 0.f;
            #pragma unroll
            for (int i = 0; i < GEO_OUT; ++i) s += Wg[r * GEO_OUT + i] * Wx[(64 + i) * 64 + n];
            Bmat[(64 + r) * 64 + n] = (unsigned short)f2b(s);
        }
        for (int idx = t; idx < 24 * 64; idx += 128)
            Bmat[72 * 64 + idx] = 0;
    }
}

// ---------------------------------------------------------------------------
// nproj: n_projb[n][j] = bf16( node_feats[n] @ Wn[:,j] + bn[j] )
// ---------------------------------------------------------------------------
__global__ __launch_bounds__(256) void nproj_kernel(
        const float* __restrict__ nf, const float* __restrict__ Wn,
        const float* __restrict__ bn, unsigned short* __restrict__ nprojb) {
    int lane = threadIdx.x & 63;
    int wid    = (blockIdx.x * blockDim.x + threadIdx.x) >> 6;
    int nwaves = (gridDim.x * blockDim.x) >> 6;
    float wcol[64];
    #pragma unroll
    for (int k = 0; k < 64; ++k) wcol[k] = Wn[k * 64 + lane];
    float bnl = bn[lane];
    for (int node = wid; node < N_NODES; node += nwaves) {
        float v = nf[(size_t)node * 64 + lane];
        float a0 = 0.f, a1 = 0.f, a2 = 0.f, a3 = bnl;
        #pragma unroll
        for (int k = 0; k < 64; k += 4) {
            a0 = fmaf(rdlane(v, k    ), wcol[k    ], a0);
            a1 = fmaf(rdlane(v, k + 1), wcol[k + 1], a1);
            a2 = fmaf(rdlane(v, k + 2), wcol[k + 2], a2);
            a3 = fmaf(rdlane(v, k + 3), wcol[k + 3], a3);
        }
        nprojb[(size_t)node * 64 + lane] = (unsigned short)f2b((a0 + a1) + (a2 + a3));
    }
}

// ---------------------------------------------------------------------------
// edge_main: per wave, tile of 16 edges; 2 tiles per wave (grid-stride).
// Non-temporal hints on streamed operands keep L2 for the nprojb gather table.
// ---------------------------------------------------------------------------
__global__ __launch_bounds__(256) void edge_kernel(
        const unsigned short* __restrict__ nprojb,
        const int*   __restrict__ eidx,
        const float* __restrict__ egeo,
        const int*   __restrict__ ebatch,
        const unsigned short* __restrict__ Bmat,
        const float* __restrict__ gamma,
        const float* __restrict__ beta2,
        float* __restrict__ out) {
    int lane = threadIdx.x & 63;
    int q  = lane >> 4;
    int mm = lane & 15;
    int wid    = (blockIdx.x * blockDim.x + threadIdx.x) >> 6;
    int nwaves = (gridDim.x * blockDim.x) >> 6;

    // B fragments: B[k = c*32 + q*8 + j][n = t*16 + mm]
    bf8 bfrag[3][4];
    #pragma unroll
    for (int c = 0; c < 3; ++c)
        #pragma unroll
        for (int t = 0; t < 4; ++t)
            #pragma unroll
            for (int j = 0; j < 8; ++j)
                bfrag[c][t][j] = (short)Bmat[(c * 32 + q * 8 + j) * 64 + t * 16 + mm];

    const int NTILES = N_EDGES / 16;
    for (int tile = wid; tile < NTILES; tile += nwaves) {
        int e0 = tile * 16;
        int e  = e0 + mm;                    // this lane's A-row edge
        int s = __builtin_nontemporal_load(eidx + e);
        int d = __builtin_nontemporal_load(eidx + N_EDGES + e);
        const u16x8* ps = (const u16x8*)(nprojb + (size_t)s * 64 + q * 8);
        const u16x8* pd = (const u16x8*)(nprojb + (size_t)d * 64 + q * 8);
        u16x8 s0 = ps[0], s1 = ps[4];        // k-chunk 0 (q*8..) and 1 (+32)
        u16x8 d0 = pd[0], d1 = pd[4];
        bf8 a0, a1, a2;
        #pragma unroll
        for (int j = 0; j < 8; ++j) {
            a0[j] = f2b(b2f(s0[j]) * b2f(d0[j]));
            a1[j] = f2b(b2f(s1[j]) * b2f(d1[j]));
            a2[j] = 0;
        }
        if (q == 0) {                        // k = 64..71 -> e_geo[e][0..7]
            f32x4 g0 = __builtin_nontemporal_load((const f32x4*)(egeo + (size_t)e * 8));
            f32x4 g1 = __builtin_nontemporal_load((const f32x4*)(egeo + (size_t)e * 8 + 4));
            #pragma unroll
            for (int j = 0; j < 4; ++j) { a2[j] = f2b(g0[j]); a2[4 + j] = f2b(g1[j]); }
        }

        f32x4 acc[4];
        #pragma unroll
        for (int t = 0; t < 4; ++t) {
            f32x4 c = {0.f, 0.f, 0.f, 0.f};
            c = __builtin_amdgcn_mfma_f32_16x16x32_bf16(a0, bfrag[0][t], c, 0, 0, 0);
            c = __builtin_amdgcn_mfma_f32_16x16x32_bf16(a1, bfrag[1][t], c, 0, 0, 0);
            c = __builtin_amdgcn_mfma_f32_16x16x32_bf16(a2, bfrag[2][t], c, 0, 0, 0);
            acc[t] = c;
        }

        #pragma unroll
        for (int i = 0; i < 4; ++i) {
            int row = q * 4 + i;             // C/D row = (lane>>4)*4 + reg
            int er  = e0 + row;
            int b   = __builtin_nontemporal_load(ebatch + er);
            const float* gp = gamma + b * 64;
            const float* bp = beta2 + b * 64;
            size_t ob = (size_t)er * 64;
            #pragma unroll
            for (int t = 0; t < 4; ++t) {
                int col = t * 16 + mm;
                float v = fmaf(acc[t][i], gp[col], bp[col]);
                __builtin_nontemporal_store(v > 0.f ? v : 0.f, out + ob + col);
            }
        }
    }
}

extern "C" void kernel_launch(void* const* d_in, const int* in_sizes, int n_in,
                              void* d_out, int out_size, void* d_ws, size_t ws_size,
                              hipStream_t stream) {
    const float* node_feats = (const float*)d_in[0];
    const int*   edge_index = (const int*)  d_in[1];
    const float* e_geo      = (const float*)d_in[2];
    const float* cond       = (const float*)d_in[3];
    const int*   ebatch     = (const int*)  d_in[4];
    const float* Wn         = (const float*)d_in[5];
    const float* bn         = (const float*)d_in[6];
    const float* Wg         = (const float*)d_in[7];
    const float* bg         = (const float*)d_in[8];
    const float* Wc         = (const float*)d_in[9];
    const float* bc         = (const float*)d_in[10];
    const float* Wx         = (const float*)d_in[11];
    float* out = (float*)d_out;

    char* ws = (char*)d_ws;
    float*          gamma  = (float*)(ws);                    // 16384 B
    float*          beta2  = (float*)(ws + 16384);            // 16384 B
    unsigned short* Bmat   = (unsigned short*)(ws + 32768);   // 12288 B
    unsigned short* nprojb = (unsigned short*)(ws + 49152);   // 12.8 MB

    hipLaunchKernelGGL(prep_kernel, dim3(65), dim3(128), 0, stream,
                       cond, Wc, bc, Wg, bg, Wx, gamma, beta2, Bmat);
    hipLaunchKernelGGL(nproj_kernel, dim3(3125), dim3(256), 0, stream,
                       node_feats, Wn, bn, nprojb);
    // 6250 blocks * 4 waves = 25000 waves -> 2 tiles/wave over 50000 tiles
    hipLaunchKernelGGL(edge_kernel, dim3(6250), dim3(256), 0, stream,
                       nprojb, edge_index, e_geo, ebatch, Bmat, gamma, beta2, out);
}

// Round 3
// 373.004 us; speedup vs baseline: 1.1173x; 1.0380x over previous
//
#include <hip/hip_runtime.h>
#include <hip/hip_bf16.h>

#define N_NODES   100000
#define N_EDGES   800000
#define NODE_DIM  64
#define EDGE_DIM  64
#define GEO_DIM   8
#define GEO_OUT   32
#define COND_DIM  512
#define N_GRAPHS  64

typedef short  bf8   __attribute__((ext_vector_type(8)));   // 8 bf16 in 4 VGPRs
typedef float  f32x4 __attribute__((ext_vector_type(4)));
typedef unsigned short u16x8 __attribute__((ext_vector_type(8)));

__device__ __forceinline__ float b2f(unsigned short u) {
    return __uint_as_float(((unsigned)u) << 16);
}
__device__ __forceinline__ short f2b(float f) {   // round-to-nearest-even f32->bf16
    unsigned u = __float_as_uint(f);
    u = (u + 0x7FFFu + ((u >> 16) & 1u)) >> 16;
    return (short)u;
}
__device__ __forceinline__ unsigned f2b2(float lo, float hi) {  // packed RNE pair
    __hip_bfloat162 h = __float22bfloat162_rn(make_float2(lo, hi));
    union { __hip_bfloat162 h; unsigned u; } cv;
    cv.h = h;
    return cv.u;
}
__device__ __forceinline__ float rdlane(float v, int l) {
    return __int_as_float(__builtin_amdgcn_readlane(__float_as_int(v), l));
}

// ---------------------------------------------------------------------------
// prep: blocks 0..63 -> gamma/beta2 per graph; block 64 -> Bfrag (bf16, 6144)
//   Bfrag stored in MFMA-fragment order: idx = ((c*4+t)*64 + lane)*8 + j
//   holds B[k=c*32+(lane>>4)*8+j][n=t*16+(lane&15)] of the folded 96x64 matrix:
//   rows 0..63 = Wx[0:64]; rows 64..71 = Wg@Wx[64:96]; rows 72..95 = 0
// ---------------------------------------------------------------------------
__global__ __launch_bounds__(128) void prep_kernel(
        const float* __restrict__ cond, const float* __restrict__ Wc,
        const float* __restrict__ bc,   const float* __restrict__ Wg,
        const float* __restrict__ bg,   const float* __restrict__ Wx,
        float* __restrict__ gamma, float* __restrict__ beta2,
        unsigned short* __restrict__ Bfrag) {
    int t = threadIdx.x;
    int g = blockIdx.x;
    if (g < N_GRAPHS) {
        __shared__ float condl[COND_DIM];
        __shared__ float gbl[128];
        for (int i = t; i < COND_DIM; i += 128) condl[i] = cond[g * COND_DIM + i];
        __syncthreads();
        float acc = bc[t];
        #pragma unroll 8
        for (int k = 0; k < COND_DIM; ++k) acc += condl[k] * Wc[k * 128 + t];
        gbl[t] = acc;
        __syncthreads();
        if (t < 64) {
            float gam = gbl[t] + 1.0f;
            float bet = gbl[64 + t];
            float cv = 0.0f;
            #pragma unroll
            for (int i = 0; i < GEO_OUT; ++i) cv += bg[i] * Wx[(64 + i) * 64 + t];
            gamma[g * 64 + t] = gam;
            beta2[g * 64 + t] = bet + cv * gam;
        }
    } else {
        for (int idx = t; idx < 6144; idx += 128) {
            int j    = idx & 7;
            int lane = (idx >> 3) & 63;
            int ct   = idx >> 9;
            int c    = ct >> 2, tt = ct & 3;
            int k = c * 32 + ((lane >> 4) & 3) * 8 + j;
            int n = tt * 16 + (lane & 15);
            float val;
            if (k < 64) {
                val = Wx[k * 64 + n];
            } else if (k < 72) {
                float s = 0.f;
                #pragma unroll
                for (int i = 0; i < GEO_OUT; ++i)
                    s += Wg[(k - 64) * GEO_OUT + i] * Wx[(64 + i) * 64 + n];
                val = s;
            } else {
                val = 0.f;
            }
            Bfrag[idx] = (unsigned short)f2b(val);
        }
    }
}

// ---------------------------------------------------------------------------
// nproj: n_projb[n][j] = bf16( node_feats[n] @ Wn[:,j] + bn[j] )
// ---------------------------------------------------------------------------
__global__ __launch_bounds__(256) void nproj_kernel(
        const float* __restrict__ nf, const float* __restrict__ Wn,
        const float* __restrict__ bn, unsigned short* __restrict__ nprojb) {
    int lane = threadIdx.x & 63;
    int wid    = (blockIdx.x * blockDim.x + threadIdx.x) >> 6;
    int nwaves = (gridDim.x * blockDim.x) >> 6;
    float wcol[64];
    #pragma unroll
    for (int k = 0; k < 64; ++k) wcol[k] = Wn[k * 64 + lane];
    float bnl = bn[lane];
    for (int node = wid; node < N_NODES; node += nwaves) {
        float v = nf[(size_t)node * 64 + lane];
        float a0 = 0.f, a1 = 0.f, a2 = 0.f, a3 = bnl;
        #pragma unroll
        for (int k = 0; k < 64; k += 4) {
            a0 = fmaf(rdlane(v, k    ), wcol[k    ], a0);
            a1 = fmaf(rdlane(v, k + 1), wcol[k + 1], a1);
            a2 = fmaf(rdlane(v, k + 2), wcol[k + 2], a2);
            a3 = fmaf(rdlane(v, k + 3), wcol[k + 3], a3);
        }
        nprojb[(size_t)node * 64 + lane] = (unsigned short)f2b((a0 + a1) + (a2 + a3));
    }
}

// ---------------------------------------------------------------------------
// edge_main: per wave, tile of 16 edges; 2 tiles/wave grid-stride.
//   MFMA 16x16x32 bf16 (layouts per m89/m91). Epilogue transposes acc through
//   a per-wave 4KB LDS tile -> float4 gamma/beta loads + 1KB coalesced stores.
// ---------------------------------------------------------------------------
__global__ __launch_bounds__(256) void edge_kernel(
        const unsigned short* __restrict__ nprojb,
        const int*   __restrict__ eidx,
        const float* __restrict__ egeo,
        const int*   __restrict__ ebatch,
        const unsigned short* __restrict__ Bfrag,
        const float* __restrict__ gamma,
        const float* __restrict__ beta2,
        float* __restrict__ out) {
    int lane = threadIdx.x & 63;
    int q  = lane >> 4;
    int mm = lane & 15;
    int wv = threadIdx.x >> 6;
    int wid    = (blockIdx.x * blockDim.x + threadIdx.x) >> 6;
    int nwaves = (gridDim.x * blockDim.x) >> 6;

    __shared__ float ldsT[4][16 * 64];      // 4KB per wave
    float* tileb = ldsT[wv];

    // B fragments, fragment-major: 12 x dwordx4
    bf8 bfrag[3][4];
    #pragma unroll
    for (int c = 0; c < 3; ++c)
        #pragma unroll
        for (int t = 0; t < 4; ++t)
            bfrag[c][t] = *(const bf8*)(Bfrag + (size_t)((c * 4 + t) * 64 + lane) * 8);

    const int NTILES = N_EDGES / 16;
    for (int tile = wid; tile < NTILES; tile += nwaves) {
        int e0 = tile * 16;
        int e  = e0 + mm;                    // this lane's A-row edge
        int s = __builtin_nontemporal_load(eidx + e);
        int d = __builtin_nontemporal_load(eidx + N_EDGES + e);
        int bq[4];                           // batch ids for epilogue rows, hoisted
        #pragma unroll
        for (int c = 0; c < 4; ++c)
            bq[c] = __builtin_nontemporal_load(ebatch + e0 + c * 4 + q);

        const u16x8* ps = (const u16x8*)(nprojb + (size_t)s * 64 + q * 8);
        const u16x8* pd = (const u16x8*)(nprojb + (size_t)d * 64 + q * 8);
        u16x8 s0 = ps[0], s1 = ps[4];        // k-chunk 0 (q*8..) and 1 (+32)
        u16x8 d0 = pd[0], d1 = pd[4];

        union { bf8 v; unsigned u[4]; } A0, A1, A2;
        #pragma unroll
        for (int j = 0; j < 8; j += 2) {
            A0.u[j >> 1] = f2b2(b2f(s0[j]) * b2f(d0[j]), b2f(s0[j + 1]) * b2f(d0[j + 1]));
            A1.u[j >> 1] = f2b2(b2f(s1[j]) * b2f(d1[j]), b2f(s1[j + 1]) * b2f(d1[j + 1]));
            A2.u[j >> 1] = 0u;
        }
        if (q == 0) {                        // k = 64..71 -> e_geo[e][0..7]
            f32x4 g0 = __builtin_nontemporal_load((const f32x4*)(egeo + (size_t)e * 8));
            f32x4 g1 = __builtin_nontemporal_load((const f32x4*)(egeo + (size_t)e * 8 + 4));
            A2.u[0] = f2b2(g0[0], g0[1]);
            A2.u[1] = f2b2(g0[2], g0[3]);
            A2.u[2] = f2b2(g1[0], g1[1]);
            A2.u[3] = f2b2(g1[2], g1[3]);
        }

        f32x4 acc[4];
        #pragma unroll
        for (int t = 0; t < 4; ++t) {
            f32x4 c = {0.f, 0.f, 0.f, 0.f};
            c = __builtin_amdgcn_mfma_f32_16x16x32_bf16(A0.v, bfrag[0][t], c, 0, 0, 0);
            c = __builtin_amdgcn_mfma_f32_16x16x32_bf16(A1.v, bfrag[1][t], c, 0, 0, 0);
            c = __builtin_amdgcn_mfma_f32_16x16x32_bf16(A2.v, bfrag[2][t], c, 0, 0, 0);
            acc[t] = c;
        }

        // stage C tile (16x64) to LDS in MFMA C-layout: row=q*4+i, col=t*16+mm
        #pragma unroll
        for (int t = 0; t < 4; ++t)
            #pragma unroll
            for (int i = 0; i < 4; ++i)
                tileb[(q * 4 + i) * 64 + t * 16 + mm] = acc[t][i];
        asm volatile("s_waitcnt lgkmcnt(0)" ::: "memory");  // wave-synchronous

        // linear re-read: lane covers floats [c*256 + lane*4 .. +3] of the tile
        #pragma unroll
        for (int c = 0; c < 4; ++c) {
            int row = c * 4 + q;             // (c*256 + lane*4)>>6
            int b   = bq[c];
            f32x4 v  = *(const f32x4*)&tileb[row * 64 + mm * 4];
            f32x4 gm = *(const f32x4*)(gamma + b * 64 + mm * 4);
            f32x4 bt = *(const f32x4*)(beta2 + b * 64 + mm * 4);
            f32x4 r;
            #pragma unroll
            for (int i = 0; i < 4; ++i) {
                float x = fmaf(v[i], gm[i], bt[i]);
                r[i] = x > 0.f ? x : 0.f;
            }
            __builtin_nontemporal_store(r, (f32x4*)(out + (size_t)e0 * 64 + c * 256 + lane * 4));
        }
    }
}

extern "C" void kernel_launch(void* const* d_in, const int* in_sizes, int n_in,
                              void* d_out, int out_size, void* d_ws, size_t ws_size,
                              hipStream_t stream) {
    const float* node_feats = (const float*)d_in[0];
    const int*   edge_index = (const int*)  d_in[1];
    const float* e_geo      = (const float*)d_in[2];
    const float* cond       = (const float*)d_in[3];
    const int*   ebatch     = (const int*)  d_in[4];
    const float* Wn         = (const float*)d_in[5];
    const float* bn         = (const float*)d_in[6];
    const float* Wg         = (const float*)d_in[7];
    const float* bg         = (const float*)d_in[8];
    const float* Wc         = (const float*)d_in[9];
    const float* bc         = (const float*)d_in[10];
    const float* Wx         = (const float*)d_in[11];
    float* out = (float*)d_out;

    char* ws = (char*)d_ws;
    float*          gamma  = (float*)(ws);                    // 16384 B
    float*          beta2  = (float*)(ws + 16384);            // 16384 B
    unsigned short* Bfrag  = (unsigned short*)(ws + 32768);   // 12288 B
    unsigned short* nprojb = (unsigned short*)(ws + 49152);   // 12.8 MB

    hipLaunchKernelGGL(prep_kernel, dim3(65), dim3(128), 0, stream,
                       cond, Wc, bc, Wg, bg, Wx, gamma, beta2, Bfrag);
    hipLaunchKernelGGL(nproj_kernel, dim3(3125), dim3(256), 0, stream,
                       node_feats, Wn, bn, nprojb);
    hipLaunchKernelGGL(edge_kernel, dim3(6250), dim3(256), 0, stream,
                       nprojb, edge_index, e_geo, ebatch, Bfrag, gamma, beta2, out);
}